// Round 2
// baseline (433.517 us; speedup 1.0000x reference)
//
#include <hip/hip_runtime.h>

#define NEGF -1000000000.0f
#define LOG2E 1.4426950408889634f
#define LN2 0.6931471805599453f

constexpr int Bn = 64;
constexpr int Tn = 1000;
constexpr int Un = 250;

// gfx950-native base-2 transcendentals: v_exp_f32 is 2^x, v_log_f32 is log2(x)
__device__ __forceinline__ float exp2fast(float x) { return __builtin_amdgcn_exp2f(x); }
__device__ __forceinline__ float log2fast(float x) { return __builtin_amdgcn_logf(x); }

// ---------------------------------------------------------------------------
// Kernel 1: per-row log-softmax denominator, in log2 units.
// Z2[b*Tn+t] = log2( 2^(-1*LOG2E) + sum_{u<L} 2^(attn[b,t,u]*LOG2E) )
// One wave (64 lanes) per row; 4 waves per 256-thread block.
// ---------------------------------------------------------------------------
__global__ void __launch_bounds__(256) zrow_kernel(const float* __restrict__ attn,
                                                   const int* __restrict__ text_lens,
                                                   float* __restrict__ Z2) {
    int wid = threadIdx.x >> 6;
    int lane = threadIdx.x & 63;
    int row = blockIdx.x * 4 + wid;            // row = b*Tn + t
    if (row >= Bn * Tn) return;
    int b = row / Tn;
    int L = text_lens[b];
    const float* p = attn + (size_t)row * Un;

    float v[4];
    float m = (lane == 0) ? -LOG2E : NEGF;     // blank column (-1.0 nat)
#pragma unroll
    for (int i = 0; i < 4; ++i) {
        int u = lane + 64 * i;
        v[i] = (u < L) ? p[u] * LOG2E : NEGF;  // u < L <= 250 -> in bounds
        m = fmaxf(m, v[i]);
    }
#pragma unroll
    for (int off = 32; off; off >>= 1) m = fmaxf(m, __shfl_xor(m, off));
    // m is the global row max (>= -LOG2E) on all lanes now.
    float s = (lane == 0) ? exp2fast(-LOG2E - m) : 0.0f;
#pragma unroll
    for (int i = 0; i < 4; ++i) s += exp2fast(v[i] - m);  // NEGF-m -> underflow to 0
#pragma unroll
    for (int off = 32; off; off >>= 1) s += __shfl_xor(s, off);
    if (lane == 0) Z2[row] = m + log2fast(s);
}

// ---------------------------------------------------------------------------
// log-sum-exp in base-2 domain
// ---------------------------------------------------------------------------
__device__ __forceinline__ float lse2_2(float a, float b) {
    float m = fmaxf(a, b);
    return m + log2fast(exp2fast(a - m) + exp2fast(b - m));
}
__device__ __forceinline__ float lse3_2(float a, float b, float c) {
    float m = fmaxf(fmaxf(a, b), c);
    return m + log2fast(exp2fast(a - m) + exp2fast(b - m) + exp2fast(c - m));
}

// ---------------------------------------------------------------------------
// Kernel 2: CTC forward recursion. One wave (64 lanes) per batch element.
// State s = lane*8 + j, j in [0,8): 512 register-resident states (>= S=501).
// Runs on RAW logits (log2 units); softmax normalization applied at the end
// as  final = (fin_raw - sum_t Z2[t]) * LN2.
// Odd state s: label column (s+1)/2 - 1 = lane*4 + (j-1)/2  -> lane reads
// attn[t, 4*lane .. 4*lane+3] (8B-aligned float2 pairs).
// States s > 2L compute garbage from in-bounds reads; they never feed states
// <= 2L (dependencies only go downward in s) nor the readout.
// ---------------------------------------------------------------------------
__global__ void __launch_bounds__(64) ctc_kernel(const float* __restrict__ attn,
                                                 const int* __restrict__ text_lens,
                                                 const int* __restrict__ mel_lens,
                                                 const float* __restrict__ Z2,
                                                 float* __restrict__ out) {
    int b = blockIdx.x;
    int lane = threadIdx.x;
    int L = text_lens[b];
    int n_t = mel_lens[b];
    const float* base = attn + (size_t)b * Tn * Un;

    float a0 = NEGF, a1 = NEGF, a2 = NEGF, a3 = NEGF;
    float a4 = NEGF, a5 = NEGF, a6 = NEGF, a7 = NEGF;
    if (lane == 0) a0 = 0.0f;

    auto load_row = [&](int t) -> float4 {
        // cols 4*lane .. 4*lane+3 of row t. Row stride is 1000B -> 8B aligned.
        const float* p = base + t * Un + lane * 4;
        if (lane < 62) {
            float2 lo = *(const float2*)p;
            float2 hi = *(const float2*)(p + 2);
            return make_float4(lo.x, lo.y, hi.x, hi.y);
        } else if (lane == 62) {
            // cols 248,249 valid; 250,251 don't exist (never needed: col<=249)
            return make_float4(p[0], p[1], 0.0f, 0.0f);
        }
        return make_float4(0.0f, 0.0f, 0.0f, 0.0f);  // lane 63: states>501
    };

    float4 vn = load_row(0);
    for (int t = 0; t < n_t; ++t) {
        float4 v = vn;
        int t2 = (t + 1 < n_t) ? t + 1 : t;
        vn = load_row(t2);  // prefetch next row while computing this step

        float prev7 = __shfl_up(a7, 1);   // alpha[8*lane - 1]
        if (lane == 0) prev7 = NEGF;

        // in-place descending update: new[j] uses old[j], old[j-1], old[j-2]
        a7 = lse3_2(a7, a6, a5) + v.w * LOG2E;   // s odd : label col 4*lane+3
        a6 = lse2_2(a6, a5) - LOG2E;             // s even: blank (-1.0 nat)
        a5 = lse3_2(a5, a4, a3) + v.z * LOG2E;
        a4 = lse2_2(a4, a3) - LOG2E;
        a3 = lse3_2(a3, a2, a1) + v.y * LOG2E;
        a2 = lse2_2(a2, a1) - LOG2E;
        a1 = lse3_2(a1, a0, prev7) + v.x * LOG2E;
        a0 = lse2_2(a0, prev7) - LOG2E;
    }

    __shared__ float sal[512];
    sal[lane * 8 + 0] = a0;
    sal[lane * 8 + 1] = a1;
    sal[lane * 8 + 2] = a2;
    sal[lane * 8 + 3] = a3;
    sal[lane * 8 + 4] = a4;
    sal[lane * 8 + 5] = a5;
    sal[lane * 8 + 6] = a6;
    sal[lane * 8 + 7] = a7;
    __syncthreads();

    // sum of log-softmax denominators over t < n_t (log2 units)
    float zs = 0.0f;
    for (int i = lane; i < n_t; i += 64) zs += Z2[b * Tn + i];
#pragma unroll
    for (int off = 32; off; off >>= 1) zs += __shfl_xor(zs, off);

    if (lane == 0) {
        float fin2 = lse2_2(sal[2 * L], sal[2 * L - 1]);
        float fin = (fin2 - zs) * LN2;           // back to natural log
        float loss = (fin < NEGF * 0.5f) ? 0.0f : (-fin / (float)L);
        atomicAdd(out, loss * (1.0f / (float)Bn));
    }
}

extern "C" void kernel_launch(void* const* d_in, const int* in_sizes, int n_in,
                              void* d_out, int out_size, void* d_ws, size_t ws_size,
                              hipStream_t stream) {
    const float* attn = (const float*)d_in[0];
    const int* text_lens = (const int*)d_in[1];
    const int* mel_lens = (const int*)d_in[2];
    float* out = (float*)d_out;
    float* Z2 = (float*)d_ws;  // Bn*Tn floats = 256 KB

    (void)hipMemsetAsync(d_out, 0, sizeof(float), stream);
    zrow_kernel<<<(Bn * Tn + 3) / 4, 256, 0, stream>>>(attn, text_lens, Z2);
    ctc_kernel<<<Bn, 64, 0, stream>>>(attn, text_lens, mel_lens, Z2, out);
}